// Round 6
// baseline (64.507 us; speedup 1.0000x reference)
//
#include <hip/hip_runtime.h>

#define GG 256
#define PP 512
#define FF 4
#define KK 6
#define NN (GG*PP)

__device__ __forceinline__ unsigned umin_(unsigned a, unsigned b){ return a<b?a:b; }
__device__ __forceinline__ unsigned umax_(unsigned a, unsigned b){ return a>b?a:b; }
__device__ __forceinline__ float finf(){ return __int_as_float(0x7f800000); }

// monotone (order-preserving) map fp32 -> u32, all non-NaN values
__device__ __forceinline__ unsigned mmap32(float d){
    int bb = __float_as_int(d);
    int t = bb >> 31;
    return (unsigned)(bb ^ (t | (int)0x80000000));
}

// u64 sorted-desc cascade (B[0] = worst of 6). Caller guarantees kv < B[0].
__device__ __forceinline__ void cas6_u64(uint64_t (&B)[6], uint64_t kv)
{
    bool c1 = kv < B[1]; bool c2 = kv < B[2]; bool c3 = kv < B[3];
    bool c4 = kv < B[4]; bool c5 = kv < B[5];
    B[0] = c1 ? B[1] : kv;
    B[1] = c2 ? B[2] : (c1 ? kv : B[1]);
    B[2] = c3 ? B[3] : (c2 ? kv : B[2]);
    B[3] = c4 ? B[4] : (c3 ? kv : B[3]);
    B[4] = c5 ? B[5] : (c4 ? kv : B[4]);
    B[5] = c5 ? kv : B[5];
}

// ascending 7-slot branchless insert on u32
#define INS7U(v){                                  \
    unsigned n0=umin_(M0,(v));                     \
    unsigned n1=umin_(M1,umax_((v),M0));           \
    unsigned n2=umin_(M2,umax_((v),M1));           \
    unsigned n3=umin_(M3,umax_((v),M2));           \
    unsigned n4=umin_(M4,umax_((v),M3));           \
    unsigned n5=umin_(M5,umax_((v),M4));           \
    unsigned n6=umin_(M6,umax_((v),M5));           \
    M0=n0;M1=n1;M2=n2;M3=n3;M4=n4;M5=n5;M6=n6; }

__global__ __launch_bounds__(512) void scan_kernel(
    const float* __restrict__ x,
    const float* __restrict__ pre_W1, const float* __restrict__ pre_b1, const float* __restrict__ pre_a1,
    const float* __restrict__ pre_W2, const float* __restrict__ pre_b2, const float* __restrict__ pre_a2,
    float* __restrict__ bn_part,     // [8][G]
    int* __restrict__ knn_idx)       // [K][N]
{
    __shared__ float4   xm2s[PP];        // -2*x                 (8 KB)
    __shared__ float    sqs[PP];         // |x|^2                (2 KB)
    __shared__ unsigned gmp[128][17];    // packed u16 group-mins (8.5 KB)
    __shared__ float    Tv[128];         // threshold per target
    __shared__ ushort   hits[128*50];    // 4 scanners x 12 +pad (12.5 KB)
    __shared__ unsigned cnt4[128][4];
    __shared__ float    wred[8][8];

    const int t = threadIdx.x;
    const int bid = blockIdx.x;
    const int g = bid >> 2, quarter = bid & 3;
    const int gbase = g * PP;
    const int w = t >> 6, lane = t & 63;
    const int s  = w & 3;                  // scanner quarter (wave-uniform)
    const int lt = (w >> 2)*64 + lane;     // local target 0..127
    const int p  = quarter*128 + lt;       // target node 0..511

    float4 xt = ((const float4*)x)[gbase + t];
    xm2s[t] = make_float4(-2.0f*xt.x, -2.0f*xt.y, -2.0f*xt.z, -2.0f*xt.w);
    sqs[t]  = xt.x*xt.x + xt.y*xt.y + xt.z*xt.z + xt.w*xt.w;

    // BN stats over pre_nn(x) — quarter-0 blocks only
    if (quarter == 0){
        float h1[FF], h2[FF];
#pragma unroll
        for (int fo=0;fo<FF;fo++){
            float m = xt.x*pre_W1[0*FF+fo] + xt.y*pre_W1[1*FF+fo]
                    + xt.z*pre_W1[2*FF+fo] + xt.w*pre_W1[3*FF+fo] + pre_b1[fo];
            h1[fo] = m >= 0.0f ? m : pre_a1[fo]*m;
        }
#pragma unroll
        for (int fo=0;fo<FF;fo++){
            float m = h1[0]*pre_W2[0*FF+fo] + h1[1]*pre_W2[1*FF+fo]
                    + h1[2]*pre_W2[2*FF+fo] + h1[3]*pre_W2[3*FF+fo] + pre_b2[fo];
            h2[fo] = m >= 0.0f ? m : pre_a2[fo]*m;
        }
        float v[8];
#pragma unroll
        for (int f=0;f<4;f++){ v[f]=h2[f]; v[4+f]=h2[f]*h2[f]; }
#pragma unroll
        for (int off=32; off; off>>=1){
#pragma unroll
            for (int f=0;f<8;f++) v[f] += __shfl_down(v[f], off);
        }
        if ((t&63)==0){
#pragma unroll
            for (int f=0;f<8;f++) wred[w][f]=v[f];
        }
    }
    __syncthreads();          // publishes xm2s/sqs AND wred
    if (quarter == 0 && t < 8){
        float a=0;
#pragma unroll
        for (int w2=0;w2<8;w2++) a += wred[w2][t];
        bn_part[t*GG + g] = a;
    }

    const int su = __builtin_amdgcn_readfirstlane(s);
    const int qb = su*128;

    const float4 xmv = xm2s[p];
    const float4 xp = make_float4(-0.5f*xmv.x, -0.5f*xmv.y, -0.5f*xmv.z, -0.5f*xmv.w);
    const float INF = finf();

    // ---- phase 1: group minima (16 cands/group, 8 groups/thread) ----
    // shifted d = |q|^2 - 2 q.p ; self = -|p|^2 = strict global min (no self test)
#pragma unroll 1
    for (int gp2=0; gp2<4; gp2++){
        unsigned packed = 0;
#pragma unroll
        for (int sub=0; sub<2; sub++){
            const int base = qb + (gp2*2+sub)*16;
            float gm = INF;
#pragma unroll
            for (int pj=0; pj<8; pj++){
                const int q0 = base + pj*2;
                float4 a = xm2s[q0], b = xm2s[q0+1];
                float2 sq = *(const float2*)&sqs[q0];
                float da = fmaf(a.x,xp.x, fmaf(a.y,xp.y, fmaf(a.z,xp.z, fmaf(a.w,xp.w, sq.x))));
                float db = fmaf(b.x,xp.x, fmaf(b.y,xp.y, fmaf(b.z,xp.z, fmaf(b.w,xp.w, sq.y))));
                gm = fminf(gm, fminf(da, db));
            }
            // round UP in monotone-u16 domain (keeps upper-bound property)
            unsigned u = mmap32(gm);
            unsigned r = (u >> 16) + ((u & 0xFFFFu) ? 1u : 0u);
            r = umin_(r, 0xFFFFu);
            packed |= r << (16*sub);
        }
        gmp[lt][su*4 + gp2] = packed;
    }
    __syncthreads();

    // ---- merge: T = 7th smallest of the 32 group-mins (incl self's group) ----
    if (t < 128){
        unsigned M0=~0u,M1=~0u,M2=~0u,M3=~0u,M4=~0u,M5=~0u,M6=~0u;
#pragma unroll
        for (int j=0;j<16;j++){
            unsigned pr = gmp[t][j];
            unsigned v0 = pr & 0xFFFFu, v1 = pr >> 16;
            INS7U(v0); INS7U(v1);
        }
        unsigned Tcmp = M6 << 16;
        // decode monotone-u32 threshold back to float (order-isomorphic)
        Tv[t] = (Tcmp & 0x80000000u) ? __uint_as_float(Tcmp ^ 0x80000000u)
                                     : __uint_as_float(~Tcmp);
    }
    __syncthreads();

    // ---- phase 2: emit candidate indices with d <= Tf (incl self) ----
    {
        const float Tf = Tv[lt];
        unsigned c = 0;
        ushort* hrow = &hits[lt*50 + su*12];
#pragma unroll 2
        for (int j=0;j<64;j++){
            const int q0 = qb + 2*j;
            float4 a = xm2s[q0], b = xm2s[q0+1];
            float2 sq = *(const float2*)&sqs[q0];
            float da = fmaf(a.x,xp.x, fmaf(a.y,xp.y, fmaf(a.z,xp.z, fmaf(a.w,xp.w, sq.x))));
            float db = fmaf(b.x,xp.x, fmaf(b.y,xp.y, fmaf(b.z,xp.z, fmaf(b.w,xp.w, sq.y))));
            bool hA = (da <= Tf), hB = (db <= Tf);
            if (hA || hB){
                int i0 = hA ? q0 : (q0+1);
                hrow[umin_(c,11u)] = (ushort)i0; c++;
                if (hA && hB){ hrow[umin_(c,11u)] = (ushort)(q0+1); c++; }
            }
        }
        cnt4[lt][su] = c;
    }
    __syncthreads();

    // ---- exact per-target selection (1 thread/target) ----
    if (t < 128){
        uint4 cc = *(const uint4*)&cnt4[t][0];
        const int pt = quarter*128 + t;
        bool ovf = (cc.x>12u)||(cc.y>12u)||(cc.z>12u)||(cc.w>12u);
        float4 xmq = xm2s[pt];
        float4 xq = make_float4(-0.5f*xmq.x, -0.5f*xmq.y, -0.5f*xmq.z, -0.5f*xmq.w);
        uint64_t B[6];
#pragma unroll
        for (int j2=0;j2<6;j2++) B[j2] = ~0ull;
        if (!ovf){
#pragma unroll
            for (int s2=0;s2<4;s2++){
                unsigned cs = (s2==0)?cc.x:(s2==1)?cc.y:(s2==2)?cc.z:cc.w;
                const ushort* hr = &hits[t*50 + s2*12];
                for (unsigned j2=0;j2<cs;j2++){
                    int idx = hr[j2];
                    float4 a = xm2s[idx];
                    float d = fmaf(a.x,xq.x, fmaf(a.y,xq.y, fmaf(a.z,xq.z, fmaf(a.w,xq.w, sqs[idx]))));
                    uint64_t key = ((uint64_t)mmap32(d) << 32) | (unsigned)idx;
                    if (idx == pt) key = ~0ull;
                    if (key < B[0]) cas6_u64(B, key);
                }
            }
        } else {
            // rare exact fallback: full rescan (scanner-buffer overflow / mass ties)
            for (int q=0;q<PP;q++){
                float4 a = xm2s[q];
                float d = fmaf(a.x,xq.x, fmaf(a.y,xq.y, fmaf(a.z,xq.z, fmaf(a.w,xq.w, sqs[q]))));
                uint64_t key = ((uint64_t)mmap32(d) << 32) | (unsigned)q;
                if (q == pt) key = ~0ull;
                if (key < B[0]) cas6_u64(B, key);
            }
        }
#pragma unroll
        for (int j2=0;j2<6;j2++)
            knn_idx[j2*NN + gbase + pt] = (int)(B[j2] & 0xFFFFFFFFull);
    }
}

__global__ __launch_bounds__(512) void graph_kernel(
    const float* __restrict__ x,
    const int* __restrict__ knn_idx,
    const float* __restrict__ bn_part,
    const float* __restrict__ pre_W1, const float* __restrict__ pre_b1, const float* __restrict__ pre_a1,
    const float* __restrict__ pre_W2, const float* __restrict__ pre_b2, const float* __restrict__ pre_a2,
    const float* __restrict__ bn_g, const float* __restrict__ bn_b,
    const float* __restrict__ act_a,
    const float* __restrict__ conv_Wm, const float* __restrict__ conv_bm,
    const float* __restrict__ hlv_W1, const float* __restrict__ hlv_b1,
    const float* __restrict__ hlv_W2, const float* __restrict__ hlv_b2,
    float* __restrict__ out)
{
    __shared__ float4 hbuf[PP];
    __shared__ float wred[8][4];
    __shared__ float pooled[20];
    __shared__ float stats[8];   // 0..3 mu, 4..7 invstd
    __shared__ float hid[20];
    const int g = blockIdx.x, p = threadIdx.x;
    const int gp = g*PP + p;

    // global BN stat reduction (2KB, L2-hot)
    if (p < 64){
        int vv = p>>3, j = p&7;
        float acc = 0.0f;
        for (int i=j;i<GG;i+=8) acc += bn_part[vv*GG + i];
        acc += __shfl_xor(acc,1); acc += __shfl_xor(acc,2); acc += __shfl_xor(acc,4);
        if (j==0) stats[vv] = acc;
    }
    __syncthreads();
    if (p < 4){
        float mu  = stats[p]   * (1.0f/NN);
        float var = stats[4+p] * (1.0f/NN) - mu*mu;
        stats[p]   = mu;
        stats[4+p] = 1.0f / sqrtf(var + 1e-5f);
    }

    float4 xt = ((const float4*)x)[gp];
    float h1[FF], h2[FF];
#pragma unroll
    for (int fo=0;fo<FF;fo++){
        float m = xt.x*pre_W1[0*FF+fo] + xt.y*pre_W1[1*FF+fo]
                + xt.z*pre_W1[2*FF+fo] + xt.w*pre_W1[3*FF+fo] + pre_b1[fo];
        h1[fo] = m >= 0.0f ? m : pre_a1[fo]*m;
    }
#pragma unroll
    for (int fo=0;fo<FF;fo++){
        float m = h1[0]*pre_W2[0*FF+fo] + h1[1]*pre_W2[1*FF+fo]
                + h1[2]*pre_W2[2*FF+fo] + h1[3]*pre_W2[3*FF+fo] + pre_b2[fo];
        h2[fo] = m >= 0.0f ? m : pre_a2[fo]*m;
    }
    __syncthreads();   // stats ready

    float hp[4];
#pragma unroll
    for (int f=0;f<4;f++)
        hp[f] = (h2[f] - stats[f]) * stats[4+f] * bn_g[f] + bn_b[f];
    hbuf[p] = make_float4(hp[0],hp[1],hp[2],hp[3]);
    int nb[KK];
#pragma unroll
    for (int j=0;j<KK;j++) nb[j] = knn_idx[j*NN + gp];

    auto block_accum = [&](const float* h, int slice){
        float v0=h[0], v1=h[1], v2=h[2], v3=h[3];
#pragma unroll
        for (int off=32; off; off>>=1){
            v0 += __shfl_down(v0,off); v1 += __shfl_down(v1,off);
            v2 += __shfl_down(v2,off); v3 += __shfl_down(v3,off);
        }
        int w = p>>6;
        if ((p&63)==0){ wred[w][0]=v0; wred[w][1]=v1; wred[w][2]=v2; wred[w][3]=v3; }
        __syncthreads();
        if (p < 4){
            float a=0;
#pragma unroll
            for (int w2=0;w2<8;w2++) a += wred[w2][p];
            pooled[slice*4+p] = a;
        }
        __syncthreads();
    };

    block_accum(hp, 0);

#pragma unroll 1
    for (int L=0; L<4; L++){
        float4 sm = make_float4(0.f,0.f,0.f,0.f);
#pragma unroll
        for (int j=0;j<KK;j++){
            float4 hn = hbuf[nb[j]];
            sm.x+=hn.x; sm.y+=hn.y; sm.z+=hn.z; sm.w+=hn.w;
        }
        const float* W  = conv_Wm + L*16;
        const float* bm = conv_bm + L*4;
        float nh[4];
#pragma unroll
        for (int fo=0;fo<4;fo++){
            float m = sm.x*W[0*4+fo] + sm.y*W[1*4+fo] + sm.z*W[2*4+fo] + sm.w*W[3*4+fo]
                    + 6.0f*bm[fo] + hp[fo];
            float a = act_a[fo];
            nh[fo] = m >= 0.0f ? m : a*m;
        }
        __syncthreads();
        hbuf[p] = make_float4(nh[0],nh[1],nh[2],nh[3]);
#pragma unroll
        for (int f=0;f<4;f++) hp[f]=nh[f];
        block_accum(hp, L+1);
    }

    if (p < 20){
        float acc = hlv_b1[p];
#pragma unroll 1
        for (int k2=0;k2<20;k2++) acc += pooled[k2]*hlv_W1[k2*20+p];
        hid[p] = acc > 0.0f ? acc : 0.0f;
    }
    __syncthreads();
    if (p == 0){
        float o = hlv_b2[0];
#pragma unroll 1
        for (int j=0;j<20;j++) o += hid[j]*hlv_W2[j];
        out[g] = o;
    }
}

extern "C" void kernel_launch(void* const* d_in, const int* in_sizes, int n_in,
                              void* d_out, int out_size, void* d_ws, size_t ws_size,
                              hipStream_t stream)
{
    const float* x      = (const float*)d_in[0];
    const float* pre_W1 = (const float*)d_in[2];
    const float* pre_b1 = (const float*)d_in[3];
    const float* pre_a1 = (const float*)d_in[4];
    const float* pre_W2 = (const float*)d_in[5];
    const float* pre_b2 = (const float*)d_in[6];
    const float* pre_a2 = (const float*)d_in[7];
    const float* bn_g   = (const float*)d_in[8];
    const float* bn_b   = (const float*)d_in[9];
    const float* act_a  = (const float*)d_in[10];
    const float* conv_Wm= (const float*)d_in[11];
    const float* conv_bm= (const float*)d_in[12];
    const float* hlv_W1 = (const float*)d_in[13];
    const float* hlv_b1 = (const float*)d_in[14];
    const float* hlv_W2 = (const float*)d_in[15];
    const float* hlv_b2 = (const float*)d_in[16];

    char* ws = (char*)d_ws;
    int*   knn     = (int*)ws;                                  // 3 MB
    float* bn_part = (float*)(ws + (size_t)6*NN*sizeof(int));   // 8 KB

    scan_kernel<<<GG*4, PP, 0, stream>>>(x, pre_W1,pre_b1,pre_a1,
                                         pre_W2,pre_b2,pre_a2, bn_part, knn);
    graph_kernel<<<GG, PP, 0, stream>>>(x, knn, bn_part,
                                        pre_W1,pre_b1,pre_a1, pre_W2,pre_b2,pre_a2,
                                        bn_g,bn_b, act_a, conv_Wm,conv_bm,
                                        hlv_W1,hlv_b1,hlv_W2,hlv_b2,
                                        (float*)d_out);
}

// Round 7
// 57.075 us; speedup vs baseline: 1.1302x; 1.1302x over previous
//
#include <hip/hip_runtime.h>

#define GG 256
#define PP 512
#define FF 4
#define KK 6
#define NN (GG*PP)

__device__ __forceinline__ unsigned umin_(unsigned a, unsigned b){ return a<b?a:b; }
__device__ __forceinline__ unsigned umax_(unsigned a, unsigned b){ return a>b?a:b; }
__device__ __forceinline__ float finf(){ return __int_as_float(0x7f800000); }

// monotone (order-preserving) map fp32 -> u32 (all non-NaN)
__device__ __forceinline__ unsigned mmap32(float d){
    int bb = __float_as_int(d);
    int t = bb >> 31;
    return (unsigned)(bb ^ (t | (int)0x80000000));
}

// u64 sorted-desc cascade (B[0] = worst of 6). Caller guarantees kv < B[0].
__device__ __forceinline__ void cas6_u64(uint64_t (&B)[6], uint64_t kv)
{
    bool c1 = kv < B[1]; bool c2 = kv < B[2]; bool c3 = kv < B[3];
    bool c4 = kv < B[4]; bool c5 = kv < B[5];
    B[0] = c1 ? B[1] : kv;
    B[1] = c2 ? B[2] : (c1 ? kv : B[1]);
    B[2] = c3 ? B[3] : (c2 ? kv : B[2]);
    B[3] = c4 ? B[4] : (c3 ? kv : B[3]);
    B[4] = c5 ? B[5] : (c4 ? kv : B[4]);
    B[5] = c5 ? kv : B[5];
}

// ascending 7-slot branchless insert on u32
#define INS7U(v){                                  \
    unsigned n0=umin_(M0,(v));                     \
    unsigned n1=umin_(M1,umax_((v),M0));           \
    unsigned n2=umin_(M2,umax_((v),M1));           \
    unsigned n3=umin_(M3,umax_((v),M2));           \
    unsigned n4=umin_(M4,umax_((v),M3));           \
    unsigned n5=umin_(M5,umax_((v),M4));           \
    unsigned n6=umin_(M6,umax_((v),M5));           \
    M0=n0;M1=n1;M2=n2;M3=n3;M4=n4;M5=n5;M6=n6; }

__global__ __launch_bounds__(512) void scan_kernel(
    const float* __restrict__ x,
    const float* __restrict__ pre_W1, const float* __restrict__ pre_b1, const float* __restrict__ pre_a1,
    const float* __restrict__ pre_W2, const float* __restrict__ pre_b2, const float* __restrict__ pre_a2,
    float* __restrict__ bn_part,     // [8][G]
    int* __restrict__ knn_idx)       // [K][N]
{
    __shared__ float4   xm2s[PP];        // -2*x      (8 KB)
    __shared__ float    sqs[PP];         // |x|^2     (2 KB)
    __shared__ ushort   gmp16[32][PP];   // group-min u16, [group][target] (32 KB)
    __shared__ float    Tv[PP];          // per-target threshold (2 KB)
    __shared__ unsigned mbuf[16][PP];    // hit masks [scanner*2+half][target] (32 KB)
    __shared__ float    wred[8][8];

    const int t = threadIdx.x;
    const int g = blockIdx.x;            // one block per graph
    const int gbase = g * PP;
    const int w = t >> 6, lane = t & 63;
    const int wu = __builtin_amdgcn_readfirstlane(w);   // scanner id (wave-uniform)
    const int qb = wu * 64;                             // candidate base

    // ---- stage graph + BN partials ----
    float4 xt = ((const float4*)x)[gbase + t];
    xm2s[t] = make_float4(-2.0f*xt.x, -2.0f*xt.y, -2.0f*xt.z, -2.0f*xt.w);
    sqs[t]  = xt.x*xt.x + xt.y*xt.y + xt.z*xt.z + xt.w*xt.w;
    {
        float h1[FF], h2[FF];
#pragma unroll
        for (int fo=0;fo<FF;fo++){
            float m = xt.x*pre_W1[0*FF+fo] + xt.y*pre_W1[1*FF+fo]
                    + xt.z*pre_W1[2*FF+fo] + xt.w*pre_W1[3*FF+fo] + pre_b1[fo];
            h1[fo] = m >= 0.0f ? m : pre_a1[fo]*m;
        }
#pragma unroll
        for (int fo=0;fo<FF;fo++){
            float m = h1[0]*pre_W2[0*FF+fo] + h1[1]*pre_W2[1*FF+fo]
                    + h1[2]*pre_W2[2*FF+fo] + h1[3]*pre_W2[3*FF+fo] + pre_b2[fo];
            h2[fo] = m >= 0.0f ? m : pre_a2[fo]*m;
        }
        float v[8];
#pragma unroll
        for (int f=0;f<4;f++){ v[f]=h2[f]; v[4+f]=h2[f]*h2[f]; }
#pragma unroll
        for (int off=32; off; off>>=1){
#pragma unroll
            for (int f=0;f<8;f++) v[f] += __shfl_down(v[f], off);
        }
        if (lane==0){
#pragma unroll
            for (int f=0;f<8;f++) wred[w][f]=v[f];
        }
    }
    __syncthreads();
    if (t < 8){
        float a=0;
#pragma unroll
        for (int w2=0;w2<8;w2++) a += wred[w2][t];
        bn_part[t*GG + g] = a;
    }

    // ---- load 8 targets into registers (tau = lane + 64j) ----
    float4 xp[8];
#pragma unroll
    for (int j=0;j<8;j++){
        float4 v = xm2s[lane + 64*j];
        xp[j] = make_float4(-0.5f*v.x, -0.5f*v.y, -0.5f*v.z, -0.5f*v.w);
    }
    const float INF = finf();

    // ---- phase 1: group minima (4 groups of 16 cands per scanner) ----
    // shifted d = |q|^2 - 2 q.p ; self = -|p|^2 = strict global min
#pragma unroll 1
    for (int grp=0; grp<4; grp++){
        float gm[8];
#pragma unroll
        for (int j=0;j<8;j++) gm[j]=INF;
#pragma unroll
        for (int i2=0;i2<8;i2++){
            const int q0 = qb + grp*16 + i2*2;
            float4 a = xm2s[q0], b = xm2s[q0+1];
            float2 sq = *(const float2*)&sqs[q0];
#pragma unroll
            for (int j=0;j<8;j++){
                float da = fmaf(a.x,xp[j].x, fmaf(a.y,xp[j].y, fmaf(a.z,xp[j].z, fmaf(a.w,xp[j].w, sq.x))));
                float db = fmaf(b.x,xp[j].x, fmaf(b.y,xp[j].y, fmaf(b.z,xp[j].z, fmaf(b.w,xp[j].w, sq.y))));
                gm[j] = fminf(gm[j], fminf(da, db));
            }
        }
#pragma unroll
        for (int j=0;j<8;j++){
            unsigned u = mmap32(gm[j]);
            unsigned r = (u >> 16) + ((u & 0xFFFFu) ? 1u : 0u);  // round UP
            r = umin_(r, 0xFFFFu);
            gmp16[wu*4 + grp][lane + 64*j] = (ushort)r;
        }
    }
    __syncthreads();

    // ---- merge: T = 7th smallest of 32 group-mins (one thread per target) ----
    {
        unsigned M0=~0u,M1=~0u,M2=~0u,M3=~0u,M4=~0u,M5=~0u,M6=~0u;
#pragma unroll
        for (int r=0;r<32;r++){
            unsigned v = gmp16[r][t];
            INS7U(v);
        }
        unsigned Tc = M6 << 16;
        Tv[t] = (Tc & 0x80000000u) ? __uint_as_float(Tc ^ 0x80000000u)
                                   : __uint_as_float(~Tc);
    }
    __syncthreads();

    // ---- phase 2: branchless hit masks (bit 31-k = cand k of half) ----
    float Tf[8];
#pragma unroll
    for (int j=0;j<8;j++) Tf[j] = Tv[lane + 64*j];

#pragma unroll 1
    for (int h=0; h<2; h++){
        unsigned m[8];
#pragma unroll
        for (int j=0;j<8;j++) m[j]=0;
#pragma unroll 4
        for (int i2=0;i2<16;i2++){
            const int q0 = qb + h*32 + i2*2;
            float4 a = xm2s[q0], b = xm2s[q0+1];
            float2 sq = *(const float2*)&sqs[q0];
#pragma unroll
            for (int j=0;j<8;j++){
                float da = fmaf(a.x,xp[j].x, fmaf(a.y,xp[j].y, fmaf(a.z,xp[j].z, fmaf(a.w,xp[j].w, sq.x))));
                float db = fmaf(b.x,xp[j].x, fmaf(b.y,xp[j].y, fmaf(b.z,xp[j].z, fmaf(b.w,xp[j].w, sq.y))));
                m[j] = m[j] + m[j] + (da <= Tf[j] ? 1u : 0u);
                m[j] = m[j] + m[j] + (db <= Tf[j] ? 1u : 0u);
            }
        }
#pragma unroll
        for (int j=0;j<8;j++) mbuf[wu*2 + h][lane + 64*j] = m[j];
    }
    __syncthreads();

    // ---- selection: walk masks, exact (dist,idx) top-6 (one thread per target) ----
    {
        float4 xmq = xm2s[t];
        float4 xq = make_float4(-0.5f*xmq.x, -0.5f*xmq.y, -0.5f*xmq.z, -0.5f*xmq.w);
        uint64_t B[6];
#pragma unroll
        for (int j2=0;j2<6;j2++) B[j2] = ~0ull;
#pragma unroll 1
        for (int r=0;r<16;r++){
            unsigned m = mbuf[r][t];
            const int base = (r>>1)*64 + (r&1)*32;
            while (m){
                int c = __builtin_clz(m);          // cand k at bit 31-k
                m &= ~(0x80000000u >> c);
                int idx = base + c;
                float4 a = xm2s[idx];
                float d = fmaf(a.x,xq.x, fmaf(a.y,xq.y, fmaf(a.z,xq.z, fmaf(a.w,xq.w, sqs[idx]))));
                uint64_t key = ((uint64_t)mmap32(d) << 32) | (unsigned)idx;
                if (idx == t) key = ~0ull;         // drop self
                if (key < B[0]) cas6_u64(B, key);
            }
        }
#pragma unroll
        for (int j2=0;j2<6;j2++)
            knn_idx[j2*NN + gbase + t] = (int)(B[j2] & 0xFFFFFFFFull);
    }
}

__global__ __launch_bounds__(512) void graph_kernel(
    const float* __restrict__ x,
    const int* __restrict__ knn_idx,
    const float* __restrict__ bn_part,
    const float* __restrict__ pre_W1, const float* __restrict__ pre_b1, const float* __restrict__ pre_a1,
    const float* __restrict__ pre_W2, const float* __restrict__ pre_b2, const float* __restrict__ pre_a2,
    const float* __restrict__ bn_g, const float* __restrict__ bn_b,
    const float* __restrict__ act_a,
    const float* __restrict__ conv_Wm, const float* __restrict__ conv_bm,
    const float* __restrict__ hlv_W1, const float* __restrict__ hlv_b1,
    const float* __restrict__ hlv_W2, const float* __restrict__ hlv_b2,
    float* __restrict__ out)
{
    __shared__ float4 hbuf[PP];
    __shared__ float wred[8][4];
    __shared__ float pooled[20];
    __shared__ float stats[8];   // 0..3 mu, 4..7 invstd
    __shared__ float hid[20];
    const int g = blockIdx.x, p = threadIdx.x;
    const int gp = g*PP + p;

    // global BN stat reduction (2KB, L2-hot)
    if (p < 64){
        int vv = p>>3, j = p&7;
        float acc = 0.0f;
        for (int i=j;i<GG;i+=8) acc += bn_part[vv*GG + i];
        acc += __shfl_xor(acc,1); acc += __shfl_xor(acc,2); acc += __shfl_xor(acc,4);
        if (j==0) stats[vv] = acc;
    }
    __syncthreads();
    if (p < 4){
        float mu  = stats[p]   * (1.0f/NN);
        float var = stats[4+p] * (1.0f/NN) - mu*mu;
        stats[p]   = mu;
        stats[4+p] = 1.0f / sqrtf(var + 1e-5f);
    }

    float4 xt = ((const float4*)x)[gp];
    float h1[FF], h2[FF];
#pragma unroll
    for (int fo=0;fo<FF;fo++){
        float m = xt.x*pre_W1[0*FF+fo] + xt.y*pre_W1[1*FF+fo]
                + xt.z*pre_W1[2*FF+fo] + xt.w*pre_W1[3*FF+fo] + pre_b1[fo];
        h1[fo] = m >= 0.0f ? m : pre_a1[fo]*m;
    }
#pragma unroll
    for (int fo=0;fo<FF;fo++){
        float m = h1[0]*pre_W2[0*FF+fo] + h1[1]*pre_W2[1*FF+fo]
                + h1[2]*pre_W2[2*FF+fo] + h1[3]*pre_W2[3*FF+fo] + pre_b2[fo];
        h2[fo] = m >= 0.0f ? m : pre_a2[fo]*m;
    }
    __syncthreads();   // stats ready

    float hp[4];
#pragma unroll
    for (int f=0;f<4;f++)
        hp[f] = (h2[f] - stats[f]) * stats[4+f] * bn_g[f] + bn_b[f];
    hbuf[p] = make_float4(hp[0],hp[1],hp[2],hp[3]);
    int nb[KK];
#pragma unroll
    for (int j=0;j<KK;j++) nb[j] = knn_idx[j*NN + gp];

    auto block_accum = [&](const float* h, int slice){
        float v0=h[0], v1=h[1], v2=h[2], v3=h[3];
#pragma unroll
        for (int off=32; off; off>>=1){
            v0 += __shfl_down(v0,off); v1 += __shfl_down(v1,off);
            v2 += __shfl_down(v2,off); v3 += __shfl_down(v3,off);
        }
        int w = p>>6;
        if ((p&63)==0){ wred[w][0]=v0; wred[w][1]=v1; wred[w][2]=v2; wred[w][3]=v3; }
        __syncthreads();
        if (p < 4){
            float a=0;
#pragma unroll
            for (int w2=0;w2<8;w2++) a += wred[w2][p];
            pooled[slice*4+p] = a;
        }
        __syncthreads();
    };

    block_accum(hp, 0);

#pragma unroll 1
    for (int L=0; L<4; L++){
        float4 sm = make_float4(0.f,0.f,0.f,0.f);
#pragma unroll
        for (int j=0;j<KK;j++){
            float4 hn = hbuf[nb[j]];
            sm.x+=hn.x; sm.y+=hn.y; sm.z+=hn.z; sm.w+=hn.w;
        }
        const float* W  = conv_Wm + L*16;
        const float* bm = conv_bm + L*4;
        float nh[4];
#pragma unroll
        for (int fo=0;fo<4;fo++){
            float m = sm.x*W[0*4+fo] + sm.y*W[1*4+fo] + sm.z*W[2*4+fo] + sm.w*W[3*4+fo]
                    + 6.0f*bm[fo] + hp[fo];
            float a = act_a[fo];
            nh[fo] = m >= 0.0f ? m : a*m;
        }
        __syncthreads();
        hbuf[p] = make_float4(nh[0],nh[1],nh[2],nh[3]);
#pragma unroll
        for (int f=0;f<4;f++) hp[f]=nh[f];
        block_accum(hp, L+1);
    }

    if (p < 20){
        float acc = hlv_b1[p];
#pragma unroll 1
        for (int k2=0;k2<20;k2++) acc += pooled[k2]*hlv_W1[k2*20+p];
        hid[p] = acc > 0.0f ? acc : 0.0f;
    }
    __syncthreads();
    if (p == 0){
        float o = hlv_b2[0];
#pragma unroll 1
        for (int j=0;j<20;j++) o += hid[j]*hlv_W2[j];
        out[g] = o;
    }
}

extern "C" void kernel_launch(void* const* d_in, const int* in_sizes, int n_in,
                              void* d_out, int out_size, void* d_ws, size_t ws_size,
                              hipStream_t stream)
{
    const float* x      = (const float*)d_in[0];
    const float* pre_W1 = (const float*)d_in[2];
    const float* pre_b1 = (const float*)d_in[3];
    const float* pre_a1 = (const float*)d_in[4];
    const float* pre_W2 = (const float*)d_in[5];
    const float* pre_b2 = (const float*)d_in[6];
    const float* pre_a2 = (const float*)d_in[7];
    const float* bn_g   = (const float*)d_in[8];
    const float* bn_b   = (const float*)d_in[9];
    const float* act_a  = (const float*)d_in[10];
    const float* conv_Wm= (const float*)d_in[11];
    const float* conv_bm= (const float*)d_in[12];
    const float* hlv_W1 = (const float*)d_in[13];
    const float* hlv_b1 = (const float*)d_in[14];
    const float* hlv_W2 = (const float*)d_in[15];
    const float* hlv_b2 = (const float*)d_in[16];

    char* ws = (char*)d_ws;
    int*   knn     = (int*)ws;                                  // 3 MB
    float* bn_part = (float*)(ws + (size_t)6*NN*sizeof(int));   // 8 KB

    scan_kernel<<<GG, PP, 0, stream>>>(x, pre_W1,pre_b1,pre_a1,
                                       pre_W2,pre_b2,pre_a2, bn_part, knn);
    graph_kernel<<<GG, PP, 0, stream>>>(x, knn, bn_part,
                                        pre_W1,pre_b1,pre_a1, pre_W2,pre_b2,pre_a2,
                                        bn_g,bn_b, act_a, conv_Wm,conv_bm,
                                        hlv_W1,hlv_b1,hlv_W2,hlv_b2,
                                        (float*)d_out);
}